// Round 3
// baseline (456.080 us; speedup 1.0000x reference)
//
#include <hip/hip_runtime.h>
#include <hip/hip_bf16.h>
#include <stdint.h>

// Band-limited linear layer: y = x @ (mask*W)^T + bias
// x: [8192, 4096] f32, W: [4096, 4096] f32 (band |o-i|<=64), bias: [4096] f32.
//
// R3 (re-run; previous round died on container acquisition, not the kernel):
// R1's pacing + R2's barrier-free engine:
//  - 1024 short-lived blocks (cb fastest, like R1) -> cohort stays in lockstep,
//    adjacent-cb x-slice overlap (128/256 cols) hits cache -> 1x x from HBM.
//  - Masked W tile (128x256 bf16, 64 KiB, XOR-swizzled) staged ONCE per block;
//    exactly one __syncthreads per block.
//  - x: global->reg->cvt->MFMA, no LDS. Prologue bursts all 16 float4 loads
//    (they fly under W staging); iteration 2 rolls its prefetch through
//    iteration 1's MFMA steps. Main loop barrier-free: no vmcnt(0) drains.
//  - PLAIN stores (R2's nontemporal stores caused partial-line writes:
//    WRITE 132->214 MB + 129 MB RFO fetches. L2 coalesces full lines fine.)
//  - Band edges: k-clamped x addresses x zeroed W (exact: 0*finite = 0).

constexpr int MROWS = 8192;
constexpr int NFEAT = 4096;
constexpr int KFEAT = 4096;
constexpr int DBAND = 64;

constexpr int BN    = 128;            // output cols per block
constexpr int KW    = 256;            // k-slice width = BN + 2*DBAND
constexpr int NS    = 8;              // k-steps of 32
constexpr int NW    = 8;              // waves per block
constexpr int WROWS = 16;             // rows per wave per iteration
constexpr int TROWS = NW * WROWS;     // 128 rows per block-iteration
constexpr int NIT   = 2;              // iterations per block (short life!)
constexpr int RPB   = TROWS * NIT;    // 256 rows per block

using bf16x8 = __attribute__((ext_vector_type(8))) short;  // 8 bf16 = 4 VGPRs
using f32x4  = __attribute__((ext_vector_type(4))) float;

__device__ __forceinline__ uint32_t pk2(float a, float b) {
    float2 t; t.x = a; t.y = b;
    __hip_bfloat162 h = __float22bfloat162_rn(t);
    union { __hip_bfloat162 h; uint32_t u; } cv;
    cv.h = h;
    return cv.u;  // low 16 = a, high 16 = b
}

__device__ __forceinline__ bf16x8 cvt8(const float4& a, const float4& b) {
    union { uint4 u; bf16x8 v; } r;
    r.u.x = pk2(a.x, a.y); r.u.y = pk2(a.z, a.w);
    r.u.z = pk2(b.x, b.y); r.u.w = pk2(b.z, b.w);
    return r.v;
}

__global__ __launch_bounds__(512)
void band_linear_kernel(const float* __restrict__ x,
                        const float* __restrict__ w,
                        const float* __restrict__ bias,
                        float* __restrict__ y)
{
    // 64 KiB: W tile [col][k] bf16, XOR-swizzled within each row (16B units)
    __shared__ short sW[BN * KW];

    const int tid  = threadIdx.x;
    const int lane = tid & 63;
    const int wv   = tid >> 6;          // wave 0..7
    const int l15  = lane & 15;
    const int lq   = lane >> 4;         // quarter 0..3

    const int cb   = blockIdx.x;        // col block 0..31 (fastest -> pacing)
    const int rg   = blockIdx.y;        // row group 0..31
    const int col0 = cb * BN;
    const int i0   = col0 - DBAND;      // global k of slice col j=0 (may be -64)

    // ---- per-step clamped k bases (uniform -> SGPRs). Clamp keeps x loads
    // in-bounds; W is zero wherever the slice col is out of range.
    int sb[NS];
    #pragma unroll
    for (int s = 0; s < NS; ++s) {
        int b = i0 + s * 32;
        b = b < 0 ? 0 : b;
        b = b > (KFEAT - 32) ? (KFEAT - 32) : b;
        sb[s] = b;
    }

    // ---- prologue: burst-issue ALL iteration-0 x loads (fly under W staging)
    const int row0 = rg * RPB + wv * WROWS + l15;
    const float* xp = x + (size_t)row0 * KFEAT;
    float4 px[2 * NS];
    #pragma unroll
    for (int s = 0; s < NS; ++s) {
        const float* p = xp + sb[s] + lq * 8;
        px[2 * s]     = *(const float4*)(p);
        px[2 * s + 1] = *(const float4*)(p + 4);
    }

    // ---- stage masked W tile into LDS (once per block)
    {
        const int wr   = tid & 127;       // tile col = output feature - col0
        const int ksel = tid >> 7;        // which 64-wide j chunk (0..3)
        const int gn   = col0 + wr;       // global output feature
        const int kbeg = i0 + ksel * 64;  // 64-aligned: fully valid or fully OOB
        short* drow    = &sW[wr * KW];
        const int swz  = (wr & 7) << 3;   // XOR swizzle of 16B-unit index
        if (kbeg >= 0 && kbeg < KFEAT) {
            const float* ws = w + (size_t)gn * KFEAT + kbeg;
            #pragma unroll
            for (int g = 0; g < 8; ++g) {
                float4 a = *(const float4*)(ws + g * 8);
                float4 b = *(const float4*)(ws + g * 8 + 4);
                const int k0 = kbeg + g * 8;
                #define MSK(v, kk) v = ((unsigned)((kk) - gn + DBAND) <= 2u * DBAND) ? v : 0.f
                MSK(a.x, k0 + 0); MSK(a.y, k0 + 1); MSK(a.z, k0 + 2); MSK(a.w, k0 + 3);
                MSK(b.x, k0 + 4); MSK(b.y, k0 + 5); MSK(b.z, k0 + 6); MSK(b.w, k0 + 7);
                #undef MSK
                uint4 p;
                p.x = pk2(a.x, a.y); p.y = pk2(a.z, a.w);
                p.z = pk2(b.x, b.y); p.w = pk2(b.z, b.w);
                *(uint4*)&drow[(ksel * 64 + g * 8) ^ swz] = p;
            }
        } else {
            const uint4 z = {0u, 0u, 0u, 0u};
            #pragma unroll
            for (int g = 0; g < 8; ++g)
                *(uint4*)&drow[(ksel * 64 + g * 8) ^ swz] = z;
        }
    }

    // ---- bias for this lane's 8 column fragments (invariant across iters)
    float bv[8];
    #pragma unroll
    for (int nf = 0; nf < 8; ++nf)
        bv[nf] = bias[col0 + nf * 16 + l15];

    __syncthreads();   // the ONLY barrier: sW ready, read-only hereafter

    f32x4 acc[8];

    #pragma unroll 1
    for (int it = 0; it < NIT; ++it) {
        #pragma unroll
        for (int nf = 0; nf < 8; ++nf) acc[nf] = (f32x4){0.f, 0.f, 0.f, 0.f};

        const float* xn = xp + (size_t)TROWS * KFEAT;  // next iteration's rows
        const bool pf = (it != NIT - 1);

        #pragma unroll
        for (int s = 0; s < NS; ++s) {
            // consume current fragment, then immediately re-issue its slot
            // for the next iteration (keeps loads in flight through compute)
            const bf16x8 af = cvt8(px[2 * s], px[2 * s + 1]);
            if (pf) {
                const float* p = xn + sb[s] + lq * 8;
                px[2 * s]     = *(const float4*)(p);
                px[2 * s + 1] = *(const float4*)(p + 4);
            }
            const int jb = s * 32 + lq * 8;
            #pragma unroll
            for (int nf = 0; nf < 8; ++nf) {
                const int jcol = nf * 16 + l15;
                const bf16x8 bf =
                    *(const bf16x8*)&sW[jcol * KW + (jb ^ ((jcol & 7) << 3))];
                acc[nf] = __builtin_amdgcn_mfma_f32_16x16x32_bf16(
                    af, bf, acc[nf], 0, 0, 0);
            }
        }

        // ---- epilogue: C layout col=lane&15, row=(lane>>4)*4+r. Plain
        // stores: L2 assembles the 128B lines (R1: WRITE == output exactly).
        const int grow = rg * RPB + it * TROWS + wv * WROWS + lq * 4;
        #pragma unroll
        for (int nf = 0; nf < 8; ++nf) {
            float* dst = y + (size_t)grow * NFEAT + (col0 + nf * 16 + l15);
            #pragma unroll
            for (int r = 0; r < 4; ++r)
                dst[(size_t)r * NFEAT] = acc[nf][r] + bv[nf];
        }
        xp = xn;
    }
}

extern "C" void kernel_launch(void* const* d_in, const int* in_sizes, int n_in,
                              void* d_out, int out_size, void* d_ws, size_t ws_size,
                              hipStream_t stream) {
    const float* x    = (const float*)d_in[0];
    const float* w    = (const float*)d_in[1];
    const float* bias = (const float*)d_in[2];
    // d_in[3] (mask) unused: band condition applied algebraically in staging.
    float* y = (float*)d_out;

    dim3 grid(NFEAT / BN, MROWS / RPB);  // 32 x 32 = 1024 blocks
    band_linear_kernel<<<grid, 512, 0, stream>>>(x, w, bias, y);
}

// Round 4
// 297.853 us; speedup vs baseline: 1.5312x; 1.5312x over previous
//
#include <hip/hip_runtime.h>
#include <hip/hip_bf16.h>
#include <stdint.h>

// Band-limited linear layer: y = x @ (mask*W)^T + bias
// x: [8192, 4096] f32, W: [4096, 4096] f32 (band |o-i|<=64), bias: [4096] f32.
//
// R4 = R1 (proven minimal-traffic: FETCH 136 + WRITE 132 MB, 91 us) with ONE
// structural change: double-buffered LDS ping-pong -> ONE barrier per chunk
// (was two), and stage(c+1) / global-load(c+2) / MFMA(c) fused into a single
// phase so cvt+ds_write interleave with ds_read+MFMA inside each wave.
// Everything else (grid order, staging map, fragments, pad-72, plain stores,
// epilogue) is byte-identical to R1. Barrier-free designs (R2/R3) are
// falsified: both blew WRITE to 214-434 MB via partial-line y evictions.

constexpr int MROWS = 8192;
constexpr int NFEAT = 4096;
constexpr int KFEAT = 4096;
constexpr int DBAND = 64;

constexpr int BM = 128;
constexpr int BN = 128;
constexpr int BK = 64;                  // K chunk per staging step
constexpr int NCH = (BN + 2 * DBAND) / BK;  // 4 chunks of 64 over the 256 slice
constexpr int LDSW = BK + 8;            // 72 shorts: +16B pad -> 2-way (free)

using bf16x8 = __attribute__((ext_vector_type(8))) short;  // 8 bf16 = 4 VGPRs
using f32x4  = __attribute__((ext_vector_type(4))) float;

__device__ __forceinline__ uint32_t pk2(float a, float b) {
    float2 t; t.x = a; t.y = b;
    __hip_bfloat162 h = __float22bfloat162_rn(t);
    union { __hip_bfloat162 h; uint32_t u; } cv;
    cv.h = h;
    return cv.u;  // low 16 = a, high 16 = b
}

__global__ __launch_bounds__(512)
void band_linear_kernel(const float* __restrict__ x,
                        const float* __restrict__ w,
                        const float* __restrict__ bias,
                        float* __restrict__ y)
{
    // ping-pong buffers: 2 x 18432 B each for A and B = 73728 B total
    __shared__ __align__(16) short sA[2][BM * LDSW];
    __shared__ __align__(16) short sB[2][BN * LDSW];

    const int tid  = threadIdx.x;
    const int lane = tid & 63;
    const int wave = tid >> 6;      // 0..7
    const int wm = wave >> 2;       // row half (64 rows)
    const int wn = wave & 3;        // col quarter (32 cols)

    const int cb = blockIdx.x;      // col block 0..31 (fastest: cohort pacing)
    const int rb = blockIdx.y;      // row block 0..63
    const int row0 = rb * BM;
    const int col0 = cb * BN;
    const int i0 = col0 - DBAND;    // first global input index of the K-slice

    // staging map: thread t -> tile row t>>2, 16-float span (t&3)*16
    const int srow = tid >> 2;           // 0..127
    const int koff = (tid & 3) * 16;     // 0,16,32,48

    const int gn  = col0 + srow;         // W output-feature row this thread stages
    const int wlo = gn - DBAND;
    const int whi = gn + DBAND;

    const float* xsrc = x + (size_t)(row0 + srow) * KFEAT + koff;
    const float* wsrc = w + (size_t)gn * KFEAT + koff;

    f32x4 acc[4][2];
    #pragma unroll
    for (int i = 0; i < 4; ++i)
        #pragma unroll
        for (int j = 0; j < 2; ++j)
            acc[i][j] = (f32x4){0.f, 0.f, 0.f, 0.f};

    float4 px[4], pw[4];  // prefetch registers (32 VGPRs)

    // uniform valid-chunk range (band edges are 64-aligned)
    int ch = (cb == 0) ? 1 : 0;
    const int che = (cb == (NFEAT / BN - 1)) ? (NCH - 1) : NCH;

    // stage regs (chunk kc) into LDS buffer pp: cvt to bf16 + band mask
    auto stage = [&](int kc, int pp) {
        const int kg = i0 + kc * BK + koff;
        uint4 pa0, pa1, pb0, pb1;
        pa0.x = pk2(px[0].x, px[0].y);  pa0.y = pk2(px[0].z, px[0].w);
        pa0.z = pk2(px[1].x, px[1].y);  pa0.w = pk2(px[1].z, px[1].w);
        pa1.x = pk2(px[2].x, px[2].y);  pa1.y = pk2(px[2].z, px[2].w);
        pa1.z = pk2(px[3].x, px[3].y);  pa1.w = pk2(px[3].z, px[3].w);
        float4 mv[4];
        #pragma unroll
        for (int g = 0; g < 4; ++g) {
            const int gk = kg + g * 4;
            float4 v = pw[g];
            v.x = (gk + 0 >= wlo && gk + 0 <= whi) ? v.x : 0.f;
            v.y = (gk + 1 >= wlo && gk + 1 <= whi) ? v.y : 0.f;
            v.z = (gk + 2 >= wlo && gk + 2 <= whi) ? v.z : 0.f;
            v.w = (gk + 3 >= wlo && gk + 3 <= whi) ? v.w : 0.f;
            mv[g] = v;
        }
        pb0.x = pk2(mv[0].x, mv[0].y);  pb0.y = pk2(mv[0].z, mv[0].w);
        pb0.z = pk2(mv[1].x, mv[1].y);  pb0.w = pk2(mv[1].z, mv[1].w);
        pb1.x = pk2(mv[2].x, mv[2].y);  pb1.y = pk2(mv[2].z, mv[2].w);
        pb1.z = pk2(mv[3].x, mv[3].y);  pb1.w = pk2(mv[3].z, mv[3].w);
        *(uint4*)&sA[pp][srow * LDSW + koff]     = pa0;
        *(uint4*)&sA[pp][srow * LDSW + koff + 8] = pa1;
        *(uint4*)&sB[pp][srow * LDSW + koff]     = pb0;
        *(uint4*)&sB[pp][srow * LDSW + koff + 8] = pb1;
    };

    auto load = [&](int kc) {
        const int kb = i0 + kc * BK;
        #pragma unroll
        for (int g = 0; g < 4; ++g) {
            px[g] = *(const float4*)(xsrc + kb + g * 4);
            pw[g] = *(const float4*)(wsrc + kb + g * 4);
        }
    };

    // ---- prologue: chunk ch -> buf0; issue loads for ch+1
    load(ch);
    stage(ch, 0);
    if (ch + 1 < che) load(ch + 1);
    __syncthreads();

    int p = 0;
    while (true) {
        const bool more1 = (ch + 1) < che;
        const bool more2 = (ch + 2) < che;

        // stage chunk ch+1 into the other buffer (readers of it finished
        // last iteration; the barrier at the end of last iteration covers it)
        if (more1) stage(ch + 1, p ^ 1);
        // issue chunk ch+2's global loads (consumed next iteration's stage)
        if (more2) load(ch + 2);

        // ---- MFMA chunk ch from buf p: 2 k-steps of 32, 4x2 grid per wave
        #pragma unroll
        for (int s = 0; s < 2; ++s) {
            bf16x8 af[4], bfr[2];
            #pragma unroll
            for (int mf = 0; mf < 4; ++mf) {
                const int r = wm * 64 + mf * 16 + (lane & 15);
                af[mf] = *(const bf16x8*)&sA[p][r * LDSW + s * 32 + (lane >> 4) * 8];
            }
            #pragma unroll
            for (int nf = 0; nf < 2; ++nf) {
                const int r = wn * 32 + nf * 16 + (lane & 15);
                bfr[nf] = *(const bf16x8*)&sB[p][r * LDSW + s * 32 + (lane >> 4) * 8];
            }
            #pragma unroll
            for (int mf = 0; mf < 4; ++mf)
                #pragma unroll
                for (int nf = 0; nf < 2; ++nf)
                    acc[mf][nf] = __builtin_amdgcn_mfma_f32_16x16x32_bf16(
                        af[mf], bfr[nf], acc[mf][nf], 0, 0, 0);
        }

        if (!more1) break;
        __syncthreads();   // the ONLY barrier per chunk
        ++ch;
        p ^= 1;
    }

    // ---- epilogue: C/D layout col=lane&15, row=(lane>>4)*4+reg (as R1)
    const int lquad = lane >> 4;
    const int lcol  = lane & 15;
    #pragma unroll
    for (int nf = 0; nf < 2; ++nf) {
        const int gc = col0 + wn * 32 + nf * 16 + lcol;
        const float bv = bias[gc];
        #pragma unroll
        for (int mf = 0; mf < 4; ++mf) {
            const int gr = row0 + wm * 64 + mf * 16 + lquad * 4;
            float* dst = y + (size_t)gr * NFEAT + gc;
            #pragma unroll
            for (int r2 = 0; r2 < 4; ++r2)
                dst[(size_t)r2 * NFEAT] = acc[mf][nf][r2] + bv;
        }
    }
}

extern "C" void kernel_launch(void* const* d_in, const int* in_sizes, int n_in,
                              void* d_out, int out_size, void* d_ws, size_t ws_size,
                              hipStream_t stream) {
    const float* x    = (const float*)d_in[0];
    const float* w    = (const float*)d_in[1];
    const float* bias = (const float*)d_in[2];
    // d_in[3] (mask) unused: band condition applied algebraically in staging.
    float* y = (float*)d_out;

    dim3 grid(NFEAT / BN, MROWS / BM);  // 32 x 64 = 2048 blocks (as R1)
    band_linear_kernel<<<grid, 512, 0, stream>>>(x, w, bias, y);
}